// Round 3
// baseline (6135.871 us; speedup 1.0000x reference)
//
#include <hip/hip_runtime.h>

// ---------------- problem constants ----------------
constexpr int N_ = 1024;   // ITEM_SIZE
constexpr int B_ = 64;     // BATCH
constexpr int T_ = 64;     // SEQ
constexpr int CAP = 96;    // cidx capacity per node (max in-degree ~61 incl self-loop)
constexpr int CAPD = 64;   // Pbuf dst capacity + ndst clamp (ndst = indeg(item) <= ~61)
constexpr int SUBS = 4;    // blocks per batch (ROUND-16: back to proven 4; 8 failed launch)
constexpr int OWN  = 256;  // nodes owned per block
constexpr size_t OUT0 = (size_t)B_ * T_ * N_;   // 4,194,304 f32 (outs), then B*N*S h (f32)

// ---------------- workspace layout (float offsets) — total 5.38 MB ----------------
// ROUND-16 note: rounds 14/15 (512-block cooperative grid, 2 blocks/CU) returned
// memset-zero output instantly regardless of ws size => cooperative launch rejected.
// This round reverts to the PROVEN 256-block / 1-block-per-CU cooperative shape.
constexpr size_t WINTo  = 0;        // w_in^T  [j][i] 128*64 = 8192
constexpr size_t WOUTTo = 8192;     // w_out^T                 8192
constexpr size_t WIHTo  = 16384;    // w_ih^T  [j][g]  64*96 = 6144
constexpr size_t WHHo   = 22528;    // w_hh row-major          3072
constexpr size_t WFCo   = 25600;    // 32
constexpr size_t BINo   = 25632;    // 64
constexpr size_t BOUTo  = 25696;    // 64
constexpr size_t BIHo   = 25760;    // 96
constexpr size_t BHHo   = 25856;    // 96
constexpr size_t BFCo   = 25952;    // 16 (1 used)
constexpr size_t INAo   = 25968;    // 1024
constexpr size_t OUTAo  = 26992;    // 1024
constexpr size_t CCNTo  = 28016;    // 1024 int (in-degree per node)
constexpr size_t DTFo   = 29040;    // 16 (dtype flag int)
constexpr size_t IEMo   = 29056;    // item_emb f32 32768
constexpr size_t REMo   = 61824;    // resp_emb f32 65536
constexpr size_t SUMEMBo= 127360;   // sum of item_emb over in-neighbors: 1024*32
constexpr size_t QCNTo  = 160128;   // [1024][4] ints: quarter boundaries (rows < 256k)
constexpr size_t OMASKo = 164224;   // u64[1024][16]: omask[v] bit j = adj[v][j] (32768 f slots)
constexpr size_t CIDXo  = 196992;   // 1024*96 int (CSC col lists, ascending) = 98304
constexpr size_t PARTo  = 295296;   // partial h-sums f32 [par2][b64][CAPD][sub4*32] = 1,048,576
constexpr size_t BARo   = 1343872;  // 64 counters, padded to 32-int (128B) stride = 2048 ints
// end = 1,345,920 floats = 5,383,680 B  (well under the 9.70 MB proven in round-13)

// ---------------- LDS layout (dynamic, float offsets) ----------------
constexpr int LDSF_H   = 0;         // h block-range [256][32] f32 = 8192
constexpr int LDSF_GI  = 8192;      // gi [256][96] bf16 = 24576 ushort = 12288 f-slots
constexpr int LDSF_FEA = 20480;     // fea_stage [16][128] f32 = 2048 (dstv reuses own slot)
constexpr int LDSF_DL  = 22528;     // dlist 64 ints
constexpr int LDSF_OUT = 22592;     // out_stage [256] f32
constexpr int LDS_FLOATS = 22848;
constexpr int LDS_BYTES  = LDS_FLOATS * 4;   // 91,392 B -> 1 block/CU (as proven at 88.6 KB)

// ---------------- helpers ----------------
__device__ __forceinline__ float bf2f(unsigned short u) {
    union { unsigned int i; float f; } x; x.i = ((unsigned int)u) << 16; return x.f;
}
__device__ __forceinline__ unsigned short f2bf(float f) {
    union { float f; unsigned int u; } x; x.f = f;
    unsigned int u = x.u;
    return (unsigned short)((u + 0x7fffu + ((u >> 16) & 1u)) >> 16);  // RNE
}
__device__ __forceinline__ float sigm(float x) { return 1.f / (1.f + __expf(-x)); }
__device__ __forceinline__ float tanhx(float x) {
    x = fminf(15.f, fmaxf(-15.f, x));
    float e = __expf(2.f * x);
    return (e - 1.f) / (e + 1.f);
}
__device__ __forceinline__ float ldg_any(const void* p, int i, int isbf) {
    return isbf ? bf2f(((const unsigned short*)p)[i]) : ((const float*)p)[i];
}

// Coherent-point (sc-flagged) 4B accessors: per-address agent coherence, no cache
// maintenance. Visibility guaranteed once vmcnt retires (i.e., after __syncthreads).
__device__ __forceinline__ void cstore(float* p, float v) {
    __hip_atomic_store((unsigned int*)p, __float_as_uint(v),
                       __ATOMIC_RELAXED, __HIP_MEMORY_SCOPE_AGENT);
}
__device__ __forceinline__ float cload(const float* p) {
    return __uint_as_float(__hip_atomic_load((const unsigned int*)p,
                       __ATOMIC_RELAXED, __HIP_MEMORY_SCOPE_AGENT));
}

// 4-block per-batch epoch barrier (fence-free; payload is sc-coherent).
// Counters padded to 128B stride so different batches' arrival atomics never
// serialize on the same L3 line.
__device__ __forceinline__ void bar4(int* c, int& ep, int tid) {
    __syncthreads();
    if (tid == 0) {
        __hip_atomic_fetch_add(c, 1, __ATOMIC_RELAXED, __HIP_MEMORY_SCOPE_AGENT);
        const int target = SUBS * (++ep);
        while (__hip_atomic_load(c, __ATOMIC_RELAXED, __HIP_MEMORY_SCOPE_AGENT) < target)
            __builtin_amdgcn_s_sleep(1);
    } else {
        ++ep;
    }
    __syncthreads();
}

// ---------------- prep: detect input float dtype from adj bit patterns ----------------
__global__ void k_detect(const unsigned int* __restrict__ adjw, float* __restrict__ ws)
{
    __shared__ int f;
    if (threadIdx.x == 0) f = 0;
    __syncthreads();
    int local = 0;
    for (int i = threadIdx.x; i < 524288; i += blockDim.x) {
        unsigned int w = adjw[i];
        if ((w & 0xFFFFu) == 0x3F80u) local = 1;
    }
    if (local) atomicOr(&f, 1);
    __syncthreads();
    if (threadIdx.x == 0) ((int*)(ws + DTFo))[0] = f;
}

// ---------------- prep: convert/pack weights -> f32 ----------------
__global__ void k_convert(const void* __restrict__ w_in,  const void* __restrict__ b_in,
                          const void* __restrict__ w_out, const void* __restrict__ b_out,
                          const void* __restrict__ in_a,  const void* __restrict__ out_a,
                          const void* __restrict__ w_ih,  const void* __restrict__ w_hh,
                          const void* __restrict__ b_ih,  const void* __restrict__ b_hh,
                          const void* __restrict__ w_fc,  const void* __restrict__ b_fc,
                          const void* __restrict__ item_emb, const void* __restrict__ resp_emb,
                          float* __restrict__ ws)
{
    const int isbf = ((const int*)(ws + DTFo))[0];
    const int tg  = blockIdx.x * blockDim.x + threadIdx.x;
    const int tot = gridDim.x * blockDim.x;
    for (int f = tg; f < 8192; f += tot) {
        int i = f & 63, j = f >> 6;
        ws[WINTo + f]  = ldg_any(w_in , i * 128 + j, isbf);
        ws[WOUTTo + f] = ldg_any(w_out, i * 128 + j, isbf);
    }
    for (int f = tg; f < 6144; f += tot) {
        int g = f % 96, j = f / 96;
        ws[WIHTo + f] = ldg_any(w_ih, g * 64 + j, isbf);
    }
    for (int f = tg; f < 3072; f += tot) ws[WHHo + f] = ldg_any(w_hh, f, isbf);
    for (int f = tg; f < 32;   f += tot) ws[WFCo + f] = ldg_any(w_fc, f, isbf);
    for (int f = tg; f < 64;   f += tot) { ws[BINo + f] = ldg_any(b_in, f, isbf); ws[BOUTo + f] = ldg_any(b_out, f, isbf); }
    for (int f = tg; f < 96;   f += tot) { ws[BIHo + f] = ldg_any(b_ih, f, isbf); ws[BHHo + f] = ldg_any(b_hh, f, isbf); }
    if (tg == 0) ws[BFCo] = ldg_any(b_fc, 0, isbf);
    for (int f = tg; f < 1024; f += tot) { ws[INAo + f] = ldg_any(in_a, f, isbf); ws[OUTAo + f] = ldg_any(out_a, f, isbf); }
    for (int f = tg; f < 32768; f += tot) ws[IEMo + f] = ldg_any(item_emb, f, isbf);
    for (int f = tg; f < 65536; f += tot) ws[REMo + f] = ldg_any(resp_emb, f, isbf);
}

// ---------------- prep: build CSC adjacency + quarter boundaries ----------------
__global__ void k_csc(const void* __restrict__ adj, float* __restrict__ ws)
{
    const int isbf = ((const int*)(ws + DTFo))[0];
    const int v = blockIdx.x;
    const int lane = threadIdx.x;
    int* ccnt = (int*)(ws + CCNTo);
    int* cidx = (int*)(ws + CIDXo);
    int* qcb  = (int*)(ws + QCNTo);   // [1024][4]
    int cnt = 0, c256 = 0, c512 = 0, c768 = 0;
    for (int ch = 0; ch < 16; ++ch) {
        int row = ch * 64 + lane;
        bool nz;
        if (isbf) nz = (((const unsigned short*)adj)[row * 1024 + v] != 0);
        else      nz = (((const float*)adj)[row * 1024 + v] != 0.f);
        unsigned long long m = __ballot(nz);
        int pos = cnt + __popcll(m & ((1ull << lane) - 1ull));
        if (nz && pos < CAP) cidx[v * CAP + pos] = row;
        cnt += __popcll(m);
        if (ch == 3)  c256 = (cnt > CAP) ? CAP : cnt;
        if (ch == 7)  c512 = (cnt > CAP) ? CAP : cnt;
        if (ch == 11) c768 = (cnt > CAP) ? CAP : cnt;
    }
    if (lane == 0) {
        ccnt[v] = (cnt > CAP) ? CAP : cnt;
        qcb[v * 4 + 0] = c256;
        qcb[v * 4 + 1] = c512;
        qcb[v * 4 + 2] = c768;
        qcb[v * 4 + 3] = 0;
    }
}

// ---------------- prep: out-neighbor bitmasks + static embedding sums ----------------
__global__ void k_emb(const void* __restrict__ adj, float* __restrict__ ws)
{
    const int isbf = ((const int*)(ws + DTFo))[0];
    const int v = blockIdx.x;
    const int lane = threadIdx.x;
    unsigned long long* om = (unsigned long long*)(ws + OMASKo);
    for (int w = 0; w < 16; ++w) {
        int col = w * 64 + lane;
        bool nz;
        if (isbf) nz = (((const unsigned short*)adj)[v * 1024 + col] != 0);
        else      nz = (((const float*)adj)[v * 1024 + col] != 0.f);
        unsigned long long m = __ballot(nz);
        if (lane == 0) om[v * 16 + w] = m;
    }
    const int cnt = ((const int*)(ws + CCNTo))[v];
    const int* cl = (const int*)(ws + CIDXo) + v * CAP;
    float acc = 0.f;
    for (int k = 0; k < cnt; ++k) {
        int u = cl[k];
        if (lane < 32) acc += ws[IEMo + u * 32 + lane];
    }
    if (lane < 32) ws[SUMEMBo + v * 32 + lane] = acc;
}

// ---------------- prep: zero (padded) barrier counters ----------------
__global__ void k_init(float* __restrict__ ws)
{
    for (int i = threadIdx.x; i < 64 * 32; i += blockDim.x)
        ((int*)(ws + BARo))[i] = 0;
}

// ---------------- main: 256 blocks = 4 per batch (cooperative, PROVEN shape) ----------------
// ROUND-16: 1024 threads/block = 16 waves = 4 waves/SIMD (round-13 had 2/SIMD).
// Same per-CU work, double the wave-level parallelism to overlap the serial
// L3/LDS/barrier latency chains that round-0 counters showed (VALUBusy 37%).
// Block owns nodes [sub*256, sub*256+256): h + gi live in LDS for the whole kernel.
__global__ __launch_bounds__(1024, 4) void gkt_main(
    const int* __restrict__ item_ids, const int* __restrict__ responses,
    float* ws, float* __restrict__ out)
{
    extern __shared__ float smem[];
    float* h_lds = smem + LDSF_H;                         // [256][32]
    unsigned short* gi16 = (unsigned short*)(smem + LDSF_GI);  // [256][96] bf16
    float* fea_stage = smem + LDSF_FEA;                   // [16][128]
    int* dlist = (int*)(smem + LDSF_DL);                  // [64]
    float* out_stage = smem + LDSF_OUT;                   // [256]

    const int tid  = threadIdx.x;
    const int lane = tid & 63;
    const int wave = tid >> 6;         // 0..15
    const int b    = blockIdx.x & 63;
    const int sub  = blockIdx.x >> 6;  // 0..3
    const int base = sub * OWN;
    const int s    = lane & 31;
    const int gsel = (lane >> 5) & 1;

    int* barc = (int*)(ws + BARo) + b * 32;               // 128B-strided counters
    const float* __restrict__ winT  = ws + WINTo;
    const float* __restrict__ woutT = ws + WOUTTo;
    const float* __restrict__ wihT  = ws + WIHTo;
    const float* __restrict__ whh   = ws + WHHo;
    const float* __restrict__ bin_f = ws + BINo;
    const float* __restrict__ bout_f= ws + BOUTo;
    const float* __restrict__ bih_f = ws + BIHo;
    const float* __restrict__ bhh_f = ws + BHHo;
    const float* __restrict__ ina_f = ws + INAo;
    const float* __restrict__ outa_f= ws + OUTAo;
    const float* __restrict__ iem   = ws + IEMo;
    const float* __restrict__ rem   = ws + REMo;
    const float* __restrict__ semb  = ws + SUMEMBo;
    const int* __restrict__ ccnt = (const int*)(ws + CCNTo);
    const int* __restrict__ cidx = (const int*)(ws + CIDXo);
    const int* __restrict__ qcb  = (const int*)(ws + QCNTo);
    const unsigned long long* __restrict__ omk = (const unsigned long long*)(ws + OMASKo);

    // init LDS: h = 0, gi = b_ih (bf16)
    for (int i = tid; i < OWN * 32; i += 1024) h_lds[i] = 0.f;
    for (int i = tid; i < OWN * 96; i += 1024) gi16[i] = f2bf(bih_f[i % 96]);

    // register-stationary GRU recurrent weights for this lane's state index s
    float wr[32], wz[32], wn[32];
    #pragma unroll
    for (int j = 0; j < 32; ++j) {
        wr[j] = whh[s * 32 + j];
        wz[j] = whh[(32 + s) * 32 + j];
        wn[j] = whh[(64 + s) * 32 + j];
    }
    const float bhr = bhh_f[s], bhz = bhh_f[32 + s], bhn = bhh_f[64 + s];
    const float wfcs = ws[WFCo + s];
    const float bfc  = ws[BFCo];
    __syncthreads();

    int ep = 0;
    const int gid = wave * 2 + gsel;   // 0..31, owns rows [gid*8, gid*8+8)

    for (int t = 0; t < T_; ++t) {
        const int item = item_ids[b * T_ + t];
        const int resp = responses[b * T_ + t];
        const int ndst0 = ccnt[item];
        const int ndst  = (ndst0 > CAPD) ? CAPD : ndst0;   // data max ~61 < 64
        if (tid < ndst) dlist[tid] = cidx[item * CAP + tid];
        __syncthreads();
        const float remv = (lane >= 32) ? rem[resp * 32 + (lane - 32)] : 0.f;

        float* Pbuf = ws + PARTo + ((size_t)(t & 1) * 64 + b) * (CAPD * 128);  // [i][128]

        // ---- phase P: partial h-sums over own 256 rows, for every dst i ----
        for (int i = wave; i < ndst; i += 16) {
            const int v = dlist[i];
            const int k0 = (sub == 0) ? 0 : qcb[v * 4 + sub - 1];
            const int k1 = (sub == 3) ? ccnt[v] : qcb[v * 4 + sub];
            float acc = 0.f;
            for (int k = k0; k < k1; ++k) {
                const int ul = cidx[v * CAP + k] - base;
                if (lane < 32) acc += h_lds[ul * 32 + lane];
            }
            if (lane < 32) cstore(Pbuf + i * 128 + sub * 32 + lane, acc);
        }
        bar4(barc, ep, tid);   // publish partials (the ONLY cross-block sync per step)

        // ---- phase A': FC + gi for dst nodes in OWN range ----
        float* fstage = fea_stage + wave * 128;
        for (int i = wave; i < ndst; i += 16) {
            const int v = dlist[i];
            if ((v >> 8) != sub) continue;           // wave-uniform skip
            const int vl = v & (OWN - 1);
            float own, agg;
            if (lane < 32) {
                own = h_lds[vl * 32 + lane];
                const float* pp = Pbuf + i * 128;
                agg = cload(pp + lane)      + cload(pp + 32 + lane)
                    + cload(pp + 64 + lane) + cload(pp + 96 + lane);
            } else {
                const int j = lane - 32;
                own = (v == item) ? remv : iem[v * 32 + j];
                const bool hasitem = (omk[item * 16 + (v >> 6)] >> (v & 63)) & 1ull;
                agg = semb[v * 32 + j] + (hasitem ? (remv - iem[item * 32 + j]) : 0.f);
            }
            fstage[lane]      = own;
            fstage[64 + lane] = agg;
            float ain = 0.f, aout = 0.f;
            const float4* f4p = (const float4*)fstage;
            #pragma unroll 8
            for (int c = 0; c < 32; ++c) {
                const float4 f = f4p[c];
                ain  += f.x * winT [(4*c+0)*64 + lane] + f.y * winT [(4*c+1)*64 + lane]
                      + f.z * winT [(4*c+2)*64 + lane] + f.w * winT [(4*c+3)*64 + lane];
                aout += f.x * woutT[(4*c+0)*64 + lane] + f.y * woutT[(4*c+1)*64 + lane]
                      + f.z * woutT[(4*c+2)*64 + lane] + f.w * woutT[(4*c+3)*64 + lane];
            }
            ain  += bin_f[lane];
            aout += bout_f[lane];
            const float dstv = outa_f[v] * aout + ina_f[v] * ain;
            // dstv reuses the own-slot (own/agg fully consumed by the loop above;
            // wave-lockstep + in-order LDS ops make this safe within the wave)
            fstage[lane] = dstv;
            float g0 = bih_f[lane];
            float g1 = (lane < 32) ? bih_f[64 + lane] : 0.f;
            const float4* d4p = (const float4*)fstage;
            #pragma unroll 8
            for (int c = 0; c < 16; ++c) {
                const float4 dv = d4p[c];
                g0 += dv.x * wihT[(4*c+0)*96 + lane] + dv.y * wihT[(4*c+1)*96 + lane]
                    + dv.z * wihT[(4*c+2)*96 + lane] + dv.w * wihT[(4*c+3)*96 + lane];
                if (lane < 32) {
                    g1 += dv.x * wihT[(4*c+0)*96 + 64 + lane] + dv.y * wihT[(4*c+1)*96 + 64 + lane]
                        + dv.z * wihT[(4*c+2)*96 + 64 + lane] + dv.w * wihT[(4*c+3)*96 + 64 + lane];
                }
            }
            gi16[vl * 96 + lane] = f2bf(g0);
            if (lane < 32) gi16[vl * 96 + 64 + lane] = f2bf(g1);
        }
        __syncthreads();   // gi_lds visible to phase B

        // ---- phase B: GRU on own rows [gid*8, gid*8+8), all LDS ----
        {
            int nl = gid * 8;
            unsigned short cS = gi16[nl * 96 + s], c32 = gi16[nl * 96 + 32 + s], c64 = gi16[nl * 96 + 64 + s];
            const float4* hrow = (const float4*)(h_lds + nl * 32);
            float4 ch[8];
            #pragma unroll
            for (int q = 0; q < 8; ++q) ch[q] = hrow[q];
            float h_own = h_lds[nl * 32 + s];

            for (int i = 0; i < 8; ++i, ++nl) {
                unsigned short nS = 0, n32 = 0, n64 = 0;
                float4 nh[8];
                float nh_own = 0.f;
                if (i < 7) {
                    nS  = gi16[(nl + 1) * 96 + s];
                    n32 = gi16[(nl + 1) * 96 + 32 + s];
                    n64 = gi16[(nl + 1) * 96 + 64 + s];
                    const float4* hnx = (const float4*)(h_lds + (nl + 1) * 32);
                    #pragma unroll
                    for (int q = 0; q < 8; ++q) nh[q] = hnx[q];
                    nh_own = h_lds[(nl + 1) * 32 + s];
                }
                float ar = bhr, az = bhz, an = bhn;
                const float* hf = (const float*)ch;
                #pragma unroll
                for (int j = 0; j < 32; ++j) {
                    const float hv = hf[j];
                    ar += wr[j] * hv; az += wz[j] * hv; an += wn[j] * hv;
                }
                const float gir = bf2f(cS), giz = bf2f(c32), gin = bf2f(c64);
                const float rg = sigm(gir + ar);
                const float zg = sigm(giz + az);
                const float ng = tanhx(gin + rg * an);
                const float hv2 = (1.f - zg) * ng + zg * h_own;
                h_lds[nl * 32 + s] = hv2;
                float red = hv2 * wfcs;
                red += __shfl_xor(red, 16); red += __shfl_xor(red, 8);
                red += __shfl_xor(red, 4);  red += __shfl_xor(red, 2);
                red += __shfl_xor(red, 1);
                if (s == 0) out_stage[nl] = sigm(red + bfc);   // staged; coalesced flush below
                if (t == T_ - 1) {
                    const int n = base + nl;
                    __builtin_nontemporal_store(hv2,
                                out + OUT0 + (size_t)b * 32768 + (size_t)n * 32 + s);
                }
                cS = nS; c32 = n32; c64 = n64; h_own = nh_own;
                #pragma unroll
                for (int q = 0; q < 8; ++q) ch[q] = nh[q];
            }
        }
        __syncthreads();   // h_lds + out_stage complete (also guards next-step phase P)

        // coalesced out flush: one contiguous 1KB store per block-step
        // (replaces 256 scattered 4B nt stores -> kills 64B-sector write amplification;
        //  out_stage is rewritten only after the next __syncthreads chain)
        if (tid < OWN)
            __builtin_nontemporal_store(out_stage[tid],
                out + (size_t)b * 65536 + (size_t)t * 1024 + base + tid);
    }
}

extern "C" void kernel_launch(void* const* d_in, const int* in_sizes, int n_in,
                              void* d_out, int out_size, void* d_ws, size_t ws_size,
                              hipStream_t stream)
{
    (void)in_sizes; (void)n_in; (void)out_size; (void)ws_size;
    const int* item_ids  = (const int*)d_in[0];
    const int* responses = (const int*)d_in[1];
    const void* adj      = d_in[2];
    const void* item_emb = d_in[3];
    const void* resp_emb = d_in[4];
    const void* w_in  = d_in[5];
    const void* b_in  = d_in[6];
    const void* w_out = d_in[7];
    const void* b_out = d_in[8];
    const void* in_a  = d_in[9];
    const void* out_a = d_in[10];
    const void* w_ih  = d_in[11];
    const void* w_hh  = d_in[12];
    const void* b_ih  = d_in[13];
    const void* b_hh  = d_in[14];
    const void* w_fc  = d_in[15];
    const void* b_fc  = d_in[16];
    float* ws = (float*)d_ws;
    float* out = (float*)d_out;

    (void)hipFuncSetAttribute((const void*)gkt_main,
                              hipFuncAttributeMaxDynamicSharedMemorySize, LDS_BYTES);

    k_detect<<<dim3(1), dim3(1024), 0, stream>>>((const unsigned int*)adj, ws);
    k_convert<<<dim3(64), dim3(256), 0, stream>>>(w_in, b_in, w_out, b_out, in_a, out_a,
                                                  w_ih, w_hh, b_ih, b_hh, w_fc, b_fc,
                                                  item_emb, resp_emb, ws);
    k_csc<<<dim3(1024), dim3(64), 0, stream>>>(adj, ws);
    k_emb<<<dim3(1024), dim3(64), 0, stream>>>(adj, ws);
    k_init<<<dim3(1), dim3(256), 0, stream>>>(ws);

    void* kargs[] = { (void*)&item_ids, (void*)&responses, (void*)&ws, (void*)&out };
    (void)hipLaunchCooperativeKernel((const void*)gkt_main, dim3(256), dim3(1024),
                                     kargs, LDS_BYTES, stream);
}

// Round 4
// 4115.457 us; speedup vs baseline: 1.4909x; 1.4909x over previous
//
#include <hip/hip_runtime.h>

// ---------------- problem constants ----------------
constexpr int N_ = 1024;   // ITEM_SIZE
constexpr int B_ = 64;     // BATCH
constexpr int T_ = 64;     // SEQ
constexpr int CAP = 96;    // cidx capacity per node (max in-degree ~61 incl self-loop)
constexpr int CAPD = 64;   // dst capacity per step (ndst = indeg(item) <= ~61)
constexpr int SUBS = 2;    // blocks per batch (ROUND-17: was 4; halves barrier straggler)
constexpr int OWN  = 512;  // nodes owned per block
constexpr size_t OUT0 = (size_t)B_ * T_ * N_;   // 4,194,304 f32 (outs), then B*N*S h (f32)

// ---------------- workspace layout (float offsets) — total 14.8 MB ----------------
// ROUND-17: gi moved LDS -> global (bf16 [64][1024][96]) to let each block own 512
// nodes. Launch shape (128 coop blocks, 512 thr, 70KB LDS) is strictly inside the
// proven 256-block/512-thr/88.6KB envelope; if this round zeros out, ws_size is
// definitively the culprit (rounds 14/15 proved zeros-failure was launch-shape).
constexpr size_t WINTo  = 0;        // w_in^T  [j][i] 128*64 = 8192
constexpr size_t WOUTTo = 8192;     // w_out^T                 8192
constexpr size_t WIHTo  = 16384;    // w_ih^T  [j][g]  64*96 = 6144
constexpr size_t WHHo   = 22528;    // w_hh row-major          3072
constexpr size_t WFCo   = 25600;    // 32
constexpr size_t BINo   = 25632;    // 64
constexpr size_t BOUTo  = 25696;    // 64
constexpr size_t BIHo   = 25760;    // 96
constexpr size_t BHHo   = 25856;    // 96
constexpr size_t BFCo   = 25952;    // 16 (1 used)
constexpr size_t INAo   = 25968;    // 1024
constexpr size_t OUTAo  = 26992;    // 1024
constexpr size_t CCNTo  = 28016;    // 1024 int (in-degree per node)
constexpr size_t DTFo   = 29040;    // 16 (dtype flag int)
constexpr size_t IEMo   = 29056;    // item_emb f32 32768
constexpr size_t REMo   = 61824;    // resp_emb f32 65536
constexpr size_t SUMEMBo= 127360;   // sum of item_emb over in-neighbors: 1024*32
constexpr size_t QCNTo  = 160128;   // [1024] int: count of in-neighbors with row < 512
constexpr size_t OMASKo = 161152;   // u64[1024][16]: omask[v] bit j = adj[v][j] (32768 f)
constexpr size_t CIDXo  = 193920;   // 1024*96 int (CSC col lists, ascending) = 98304
constexpr size_t GIo    = 292224;   // gi bf16 [64][1024][96] = 6,291,456 us = 3,145,728 f
constexpr size_t PARTo  = 3437952;  // published half-partials f32 [par2][b64][CAPD][32] = 262,144
constexpr size_t BARo   = 3700096;  // 64 counters, padded to 32-int (128B) stride = 2048
// end = 3,702,144 floats = 14,808,576 B

// ---------------- LDS layout (dynamic, float offsets) ----------------
constexpr int LDSF_H   = 0;         // h block-range [512][32] f32 = 16384
constexpr int LDSF_FEA = 16384;     // fea_stage [8][128] f32 = 1024 (dstv reuses own slot)
constexpr int LDSF_OUT = 17408;     // out_stage [512] f32
constexpr int LDS_FLOATS = 17920;
constexpr int LDS_BYTES  = LDS_FLOATS * 4;   // 71,680 B (< 88.6 KB proven)

// ---------------- helpers ----------------
__device__ __forceinline__ float bf2f(unsigned short u) {
    union { unsigned int i; float f; } x; x.i = ((unsigned int)u) << 16; return x.f;
}
__device__ __forceinline__ unsigned short f2bf(float f) {
    union { float f; unsigned int u; } x; x.f = f;
    unsigned int u = x.u;
    return (unsigned short)((u + 0x7fffu + ((u >> 16) & 1u)) >> 16);  // RNE
}
__device__ __forceinline__ float sigm(float x) { return 1.f / (1.f + __expf(-x)); }
__device__ __forceinline__ float tanhx(float x) {
    x = fminf(15.f, fmaxf(-15.f, x));
    float e = __expf(2.f * x);
    return (e - 1.f) / (e + 1.f);
}
__device__ __forceinline__ float ldg_any(const void* p, int i, int isbf) {
    return isbf ? bf2f(((const unsigned short*)p)[i]) : ((const float*)p)[i];
}

// Coherent-point (sc-flagged) 4B accessors for the cross-block Pbuf payload.
__device__ __forceinline__ void cstore(float* p, float v) {
    __hip_atomic_store((unsigned int*)p, __float_as_uint(v),
                       __ATOMIC_RELAXED, __HIP_MEMORY_SCOPE_AGENT);
}
__device__ __forceinline__ float cload(const float* p) {
    return __uint_as_float(__hip_atomic_load((const unsigned int*)p,
                       __ATOMIC_RELAXED, __HIP_MEMORY_SCOPE_AGENT));
}

// 2-block per-batch epoch barrier (fence-free; payload is sc-coherent).
__device__ __forceinline__ void bar2(int* c, int& ep, int tid) {
    __syncthreads();
    if (tid == 0) {
        __hip_atomic_fetch_add(c, 1, __ATOMIC_RELAXED, __HIP_MEMORY_SCOPE_AGENT);
        const int target = SUBS * (++ep);
        while (__hip_atomic_load(c, __ATOMIC_RELAXED, __HIP_MEMORY_SCOPE_AGENT) < target)
            __builtin_amdgcn_s_sleep(1);
    } else {
        ++ep;
    }
    __syncthreads();
}

// ---------------- prep: detect input float dtype from adj bit patterns ----------------
__global__ void k_detect(const unsigned int* __restrict__ adjw, float* __restrict__ ws)
{
    __shared__ int f;
    if (threadIdx.x == 0) f = 0;
    __syncthreads();
    int local = 0;
    for (int i = threadIdx.x; i < 524288; i += blockDim.x) {
        unsigned int w = adjw[i];
        if ((w & 0xFFFFu) == 0x3F80u) local = 1;
    }
    if (local) atomicOr(&f, 1);
    __syncthreads();
    if (threadIdx.x == 0) ((int*)(ws + DTFo))[0] = f;
}

// ---------------- prep: convert/pack weights -> f32 ----------------
__global__ void k_convert(const void* __restrict__ w_in,  const void* __restrict__ b_in,
                          const void* __restrict__ w_out, const void* __restrict__ b_out,
                          const void* __restrict__ in_a,  const void* __restrict__ out_a,
                          const void* __restrict__ w_ih,  const void* __restrict__ w_hh,
                          const void* __restrict__ b_ih,  const void* __restrict__ b_hh,
                          const void* __restrict__ w_fc,  const void* __restrict__ b_fc,
                          const void* __restrict__ item_emb, const void* __restrict__ resp_emb,
                          float* __restrict__ ws)
{
    const int isbf = ((const int*)(ws + DTFo))[0];
    const int tg  = blockIdx.x * blockDim.x + threadIdx.x;
    const int tot = gridDim.x * blockDim.x;
    for (int f = tg; f < 8192; f += tot) {
        int i = f & 63, j = f >> 6;
        ws[WINTo + f]  = ldg_any(w_in , i * 128 + j, isbf);
        ws[WOUTTo + f] = ldg_any(w_out, i * 128 + j, isbf);
    }
    for (int f = tg; f < 6144; f += tot) {
        int g = f % 96, j = f / 96;
        ws[WIHTo + f] = ldg_any(w_ih, g * 64 + j, isbf);
    }
    for (int f = tg; f < 3072; f += tot) ws[WHHo + f] = ldg_any(w_hh, f, isbf);
    for (int f = tg; f < 32;   f += tot) ws[WFCo + f] = ldg_any(w_fc, f, isbf);
    for (int f = tg; f < 64;   f += tot) { ws[BINo + f] = ldg_any(b_in, f, isbf); ws[BOUTo + f] = ldg_any(b_out, f, isbf); }
    for (int f = tg; f < 96;   f += tot) { ws[BIHo + f] = ldg_any(b_ih, f, isbf); ws[BHHo + f] = ldg_any(b_hh, f, isbf); }
    if (tg == 0) ws[BFCo] = ldg_any(b_fc, 0, isbf);
    for (int f = tg; f < 1024; f += tot) { ws[INAo + f] = ldg_any(in_a, f, isbf); ws[OUTAo + f] = ldg_any(out_a, f, isbf); }
    for (int f = tg; f < 32768; f += tot) ws[IEMo + f] = ldg_any(item_emb, f, isbf);
    for (int f = tg; f < 65536; f += tot) ws[REMo + f] = ldg_any(resp_emb, f, isbf);
}

// ---------------- prep: build CSC adjacency + half boundary ----------------
__global__ void k_csc(const void* __restrict__ adj, float* __restrict__ ws)
{
    const int isbf = ((const int*)(ws + DTFo))[0];
    const int v = blockIdx.x;
    const int lane = threadIdx.x;
    int* ccnt = (int*)(ws + CCNTo);
    int* cidx = (int*)(ws + CIDXo);
    int* qcb  = (int*)(ws + QCNTo);   // [1024]: #neighbors with row < 512
    int cnt = 0, c512 = 0;
    for (int ch = 0; ch < 16; ++ch) {
        int row = ch * 64 + lane;
        bool nz;
        if (isbf) nz = (((const unsigned short*)adj)[row * 1024 + v] != 0);
        else      nz = (((const float*)adj)[row * 1024 + v] != 0.f);
        unsigned long long m = __ballot(nz);
        int pos = cnt + __popcll(m & ((1ull << lane) - 1ull));
        if (nz && pos < CAP) cidx[v * CAP + pos] = row;
        cnt += __popcll(m);
        if (ch == 7) c512 = (cnt > CAP) ? CAP : cnt;
    }
    if (lane == 0) {
        ccnt[v] = (cnt > CAP) ? CAP : cnt;
        qcb[v] = c512;
    }
}

// ---------------- prep: out-neighbor bitmasks + static embedding sums ----------------
__global__ void k_emb(const void* __restrict__ adj, float* __restrict__ ws)
{
    const int isbf = ((const int*)(ws + DTFo))[0];
    const int v = blockIdx.x;
    const int lane = threadIdx.x;
    unsigned long long* om = (unsigned long long*)(ws + OMASKo);
    for (int w = 0; w < 16; ++w) {
        int col = w * 64 + lane;
        bool nz;
        if (isbf) nz = (((const unsigned short*)adj)[v * 1024 + col] != 0);
        else      nz = (((const float*)adj)[v * 1024 + col] != 0.f);
        unsigned long long m = __ballot(nz);
        if (lane == 0) om[v * 16 + w] = m;
    }
    const int cnt = ((const int*)(ws + CCNTo))[v];
    const int* cl = (const int*)(ws + CIDXo) + v * CAP;
    float acc = 0.f;
    for (int k = 0; k < cnt; ++k) {
        int u = cl[k];
        if (lane < 32) acc += ws[IEMo + u * 32 + lane];
    }
    if (lane < 32) ws[SUMEMBo + v * 32 + lane] = acc;
}

// ---------------- prep: zero barrier counters + init gi = b_ih (bf16) ----------------
__global__ void k_init(float* __restrict__ ws)
{
    const int tg  = blockIdx.x * blockDim.x + threadIdx.x;
    const int tot = gridDim.x * blockDim.x;
    for (int i = tg; i < 64 * 32; i += tot) ((int*)(ws + BARo))[i] = 0;
    unsigned short* gi = (unsigned short*)(ws + GIo);
    for (size_t i = tg; i < (size_t)64 * 1024 * 96; i += tot)
        gi[i] = f2bf(ws[BIHo + (i % 96)]);
}

// ---------------- main: 128 blocks = 2 per batch (cooperative) ----------------
// Block owns nodes [sub*512, sub*512+512): h f32 in LDS; gi bf16 in GLOBAL
// (written by A', read by B on the same CU; __syncthreads gives workgroup-scope
// visibility). Cross-block traffic per step = ONE published half-partial per dst
// (the owner keeps its own half in registers) + one bar2.
__global__ __launch_bounds__(512, 2) void gkt_main(
    const int* __restrict__ item_ids, const int* __restrict__ responses,
    float* ws, float* __restrict__ out)
{
    extern __shared__ float smem[];
    float* h_lds = smem + LDSF_H;                         // [512][32]
    float* fea_stage = smem + LDSF_FEA;                   // [8][128]
    float* out_stage = smem + LDSF_OUT;                   // [512]

    const int tid  = threadIdx.x;
    const int lane = tid & 63;
    const int wave = tid >> 6;         // 0..7
    const int b    = blockIdx.x & 63;
    const int sub  = blockIdx.x >> 6;  // 0..1
    const int base = sub * OWN;
    const int s    = lane & 31;
    const int gsel = (lane >> 5) & 1;

    int* barc = (int*)(ws + BARo) + b * 32;               // 128B-strided counters
    const float* __restrict__ winT  = ws + WINTo;
    const float* __restrict__ woutT = ws + WOUTTo;
    const float* __restrict__ wihT  = ws + WIHTo;
    const float* __restrict__ whh   = ws + WHHo;
    const float* __restrict__ bin_f = ws + BINo;
    const float* __restrict__ bout_f= ws + BOUTo;
    const float* __restrict__ bih_f = ws + BIHo;
    const float* __restrict__ bhh_f = ws + BHHo;
    const float* __restrict__ ina_f = ws + INAo;
    const float* __restrict__ outa_f= ws + OUTAo;
    const float* __restrict__ iem   = ws + IEMo;
    const float* __restrict__ rem   = ws + REMo;
    const float* __restrict__ semb  = ws + SUMEMBo;
    const int* __restrict__ ccnt = (const int*)(ws + CCNTo);
    const int* __restrict__ cidx = (const int*)(ws + CIDXo);
    const int* __restrict__ qcb  = (const int*)(ws + QCNTo);
    const unsigned long long* __restrict__ omk = (const unsigned long long*)(ws + OMASKo);
    unsigned short* __restrict__ giB = (unsigned short*)(ws + GIo) + (size_t)b * 1024 * 96;

    // init LDS h = 0 (gi already b_ih from k_init)
    for (int i = tid; i < OWN * 32; i += 512) h_lds[i] = 0.f;

    // register-stationary GRU recurrent weights for this lane's state index s
    float wr[32], wz[32], wn[32];
    #pragma unroll
    for (int j = 0; j < 32; ++j) {
        wr[j] = whh[s * 32 + j];
        wz[j] = whh[(32 + s) * 32 + j];
        wn[j] = whh[(64 + s) * 32 + j];
    }
    const float bhr = bhh_f[s], bhz = bhh_f[32 + s], bhn = bhh_f[64 + s];
    const float wfcs = ws[WFCo + s];
    const float bfc  = ws[BFCo];
    __syncthreads();

    int ep = 0;
    const int gid = wave * 2 + gsel;   // 0..15, owns rows [gid*32, gid*32+32)

    for (int t = 0; t < T_; ++t) {
        const int item = item_ids[b * T_ + t];
        const int resp = responses[b * T_ + t];
        const int ndst0 = ccnt[item];
        const int ndst  = (ndst0 > CAPD) ? CAPD : ndst0;   // data max ~61 < 64
        const float remv = (lane >= 32) ? rem[resp * 32 + (lane - 32)] : 0.f;

        float* Pbuf = ws + PARTo + ((size_t)(t & 1) * 64 + b) * (CAPD * 32);  // [i][32]
        float regP[8];   // own-half partials for own dsts (slot (i-wave)/8)

        // ---- phase P: own-half h-sums for every dst i; publish only foreign dsts ----
        for (int i = wave; i < ndst; i += 8) {
            const int v = cidx[item * CAP + i];
            const int k0 = (sub == 0) ? 0 : qcb[v];
            const int k1 = (sub == 0) ? qcb[v] : ccnt[v];
            float acc = 0.f;
            for (int k = k0; k < k1; ++k) {
                const int ul = cidx[v * CAP + k] - base;
                if (lane < 32) acc += h_lds[ul * 32 + lane];
            }
            if (lane < 32) {
                if ((v >> 9) == sub) regP[(i - wave) >> 3] = acc;   // own dst: keep
                else cstore(Pbuf + i * 32 + lane, acc);             // foreign: publish
            }
        }
        bar2(barc, ep, tid);   // the ONLY cross-block sync per step

        // ---- phase A': FC + gi for dst nodes in OWN range ----
        float* fstage = fea_stage + wave * 128;
        for (int i = wave; i < ndst; i += 8) {
            const int v = cidx[item * CAP + i];
            if ((v >> 9) != sub) continue;           // wave-uniform skip
            const int vl = v - base;
            float own, agg;
            if (lane < 32) {
                own = h_lds[vl * 32 + lane];
                agg = regP[(i - wave) >> 3] + cload(Pbuf + i * 32 + lane);
            } else {
                const int j = lane - 32;
                own = (v == item) ? remv : iem[v * 32 + j];
                const bool hasitem = (omk[item * 16 + (v >> 6)] >> (v & 63)) & 1ull;
                agg = semb[v * 32 + j] + (hasitem ? (remv - iem[item * 32 + j]) : 0.f);
            }
            fstage[lane]      = own;
            fstage[64 + lane] = agg;
            float ain = 0.f, aout = 0.f;
            const float4* f4p = (const float4*)fstage;
            #pragma unroll 8
            for (int c = 0; c < 32; ++c) {
                const float4 f = f4p[c];
                ain  += f.x * winT [(4*c+0)*64 + lane] + f.y * winT [(4*c+1)*64 + lane]
                      + f.z * winT [(4*c+2)*64 + lane] + f.w * winT [(4*c+3)*64 + lane];
                aout += f.x * woutT[(4*c+0)*64 + lane] + f.y * woutT[(4*c+1)*64 + lane]
                      + f.z * woutT[(4*c+2)*64 + lane] + f.w * woutT[(4*c+3)*64 + lane];
            }
            ain  += bin_f[lane];
            aout += bout_f[lane];
            const float dstv = outa_f[v] * aout + ina_f[v] * ain;
            fstage[lane] = dstv;   // reuse own slot (proven in round-16)
            float g0 = bih_f[lane];
            float g1 = (lane < 32) ? bih_f[64 + lane] : 0.f;
            const float4* d4p = (const float4*)fstage;
            #pragma unroll 8
            for (int c = 0; c < 16; ++c) {
                const float4 dv = d4p[c];
                g0 += dv.x * wihT[(4*c+0)*96 + lane] + dv.y * wihT[(4*c+1)*96 + lane]
                    + dv.z * wihT[(4*c+2)*96 + lane] + dv.w * wihT[(4*c+3)*96 + lane];
                if (lane < 32) {
                    g1 += dv.x * wihT[(4*c+0)*96 + 64 + lane] + dv.y * wihT[(4*c+1)*96 + 64 + lane]
                        + dv.z * wihT[(4*c+2)*96 + 64 + lane] + dv.w * wihT[(4*c+3)*96 + 64 + lane];
                }
            }
            unsigned short* gp = giB + (size_t)v * 96;
            gp[lane] = f2bf(g0);
            if (lane < 32) gp[64 + lane] = f2bf(g1);
        }
        __syncthreads();   // gi (global, workgroup scope) + h reads done before B writes h

        // ---- phase B: GRU on own rows [gid*32, gid*32+32), h in LDS, gi from global ----
        {
            int nl = gid * 32;
            const unsigned short* r0 = giB + (size_t)(base + nl) * 96;
            unsigned short cS = r0[s], c32 = r0[32 + s], c64 = r0[64 + s];
            const float4* hrow = (const float4*)(h_lds + nl * 32);
            float4 ch[8];
            #pragma unroll
            for (int q = 0; q < 8; ++q) ch[q] = hrow[q];
            float h_own = h_lds[nl * 32 + s];

            for (int i = 0; i < 32; ++i, ++nl) {
                unsigned short nS = 0, n32 = 0, n64 = 0;
                float4 nh[8];
                float nh_own = 0.f;
                if (i < 31) {
                    const unsigned short* r1 = giB + (size_t)(base + nl + 1) * 96;
                    nS  = r1[s];
                    n32 = r1[32 + s];
                    n64 = r1[64 + s];
                    const float4* hnx = (const float4*)(h_lds + (nl + 1) * 32);
                    #pragma unroll
                    for (int q = 0; q < 8; ++q) nh[q] = hnx[q];
                    nh_own = h_lds[(nl + 1) * 32 + s];
                }
                float ar = bhr, az = bhz, an = bhn;
                const float* hf = (const float*)ch;
                #pragma unroll
                for (int j = 0; j < 32; ++j) {
                    const float hv = hf[j];
                    ar += wr[j] * hv; az += wz[j] * hv; an += wn[j] * hv;
                }
                const float gir = bf2f(cS), giz = bf2f(c32), gin = bf2f(c64);
                const float rg = sigm(gir + ar);
                const float zg = sigm(giz + az);
                const float ng = tanhx(gin + rg * an);
                const float hv2 = (1.f - zg) * ng + zg * h_own;
                h_lds[nl * 32 + s] = hv2;
                float red = hv2 * wfcs;
                red += __shfl_xor(red, 16); red += __shfl_xor(red, 8);
                red += __shfl_xor(red, 4);  red += __shfl_xor(red, 2);
                red += __shfl_xor(red, 1);
                if (s == 0) out_stage[nl] = sigm(red + bfc);   // staged; coalesced flush below
                if (t == T_ - 1) {
                    const int n = base + nl;
                    __builtin_nontemporal_store(hv2,
                                out + OUT0 + (size_t)b * 32768 + (size_t)n * 32 + s);
                }
                cS = nS; c32 = n32; c64 = n64; h_own = nh_own;
                #pragma unroll
                for (int q = 0; q < 8; ++q) ch[q] = nh[q];
            }
        }
        __syncthreads();   // h_lds + out_stage complete (also guards next-step phase P)

        // coalesced out flush: one contiguous 2KB store per block-step
        __builtin_nontemporal_store(out_stage[tid],
            out + (size_t)b * 65536 + (size_t)t * 1024 + base + tid);
    }
}

extern "C" void kernel_launch(void* const* d_in, const int* in_sizes, int n_in,
                              void* d_out, int out_size, void* d_ws, size_t ws_size,
                              hipStream_t stream)
{
    (void)in_sizes; (void)n_in; (void)out_size; (void)ws_size;
    const int* item_ids  = (const int*)d_in[0];
    const int* responses = (const int*)d_in[1];
    const void* adj      = d_in[2];
    const void* item_emb = d_in[3];
    const void* resp_emb = d_in[4];
    const void* w_in  = d_in[5];
    const void* b_in  = d_in[6];
    const void* w_out = d_in[7];
    const void* b_out = d_in[8];
    const void* in_a  = d_in[9];
    const void* out_a = d_in[10];
    const void* w_ih  = d_in[11];
    const void* w_hh  = d_in[12];
    const void* b_ih  = d_in[13];
    const void* b_hh  = d_in[14];
    const void* w_fc  = d_in[15];
    const void* b_fc  = d_in[16];
    float* ws = (float*)d_ws;
    float* out = (float*)d_out;

    (void)hipFuncSetAttribute((const void*)gkt_main,
                              hipFuncAttributeMaxDynamicSharedMemorySize, LDS_BYTES);

    k_detect<<<dim3(1), dim3(1024), 0, stream>>>((const unsigned int*)adj, ws);
    k_convert<<<dim3(64), dim3(256), 0, stream>>>(w_in, b_in, w_out, b_out, in_a, out_a,
                                                  w_ih, w_hh, b_ih, b_hh, w_fc, b_fc,
                                                  item_emb, resp_emb, ws);
    k_csc<<<dim3(1024), dim3(64), 0, stream>>>(adj, ws);
    k_emb<<<dim3(1024), dim3(64), 0, stream>>>(adj, ws);
    k_init<<<dim3(256), dim3(256), 0, stream>>>(ws);

    void* kargs[] = { (void*)&item_ids, (void*)&responses, (void*)&ws, (void*)&out };
    (void)hipLaunchCooperativeKernel((const void*)gkt_main, dim3(128), dim3(512),
                                     kargs, LDS_BYTES, stream);
}